// Round 2
// baseline (9266.196 us; speedup 1.0000x reference)
//
#include <hip/hip_runtime.h>
#include <math.h>

typedef __bf16 bf16;
typedef __attribute__((ext_vector_type(4))) __bf16 bf16x4;
typedef __attribute__((ext_vector_type(8))) __bf16 bf16x8;
typedef __attribute__((ext_vector_type(4))) float f32x4;

#define T_STEPS 128
#define B_SZ    256
#define V_SZ    256
#define N_SZ    1024
#define NROWS   (T_STEPS * B_SZ)   // 32768
#define LDSS    72                 // padded LDS stride in elements (64 + 8)

// persistent-RNN geometry
#define MT      16                 // batch rows per group
#define NGROUP  (B_SZ / MT)        // 16 row groups
#define NW      64                 // output cols per block
#define NB      (N_SZ / NW)        // 16 col blocks per group
#define KW      128                // K-range per wave (8 waves)
#define RSTR    68                 // padded reduction stride

__device__ __forceinline__ float fast_tanh(float x) {
    float e = __expf(2.0f * x);
    return 1.0f - 2.0f / (e + 1.0f);   // exact at +-inf, no NaN
}

// ---------------- fp32 -> bf16 contiguous convert ----------------
__global__ void k_convert(const float* __restrict__ src, bf16* __restrict__ dst, int n) {
    int i = (blockIdx.x * blockDim.x + threadIdx.x) * 4;
    if (i < n) {
        float4 v = *(const float4*)(src + i);
        bf16x4 o;
        o.x = (bf16)v.x; o.y = (bf16)v.y; o.z = (bf16)v.z; o.w = (bf16)v.w;
        *(bf16x4*)(dst + i) = o;
    }
}

// ---------------- fp32 (R x C) -> bf16 transpose (C x R) ----------------
__global__ void k_transpose_cvt(const float* __restrict__ src, bf16* __restrict__ dst,
                                int R, int C) {
    __shared__ float tile[32][33];
    int c0 = blockIdx.x * 32;
    int r0 = blockIdx.y * 32;
    int tx = threadIdx.x & 31;
    int ty = threadIdx.x >> 5;   // 0..7
#pragma unroll
    for (int i = 0; i < 32; i += 8)
        tile[ty + i][tx] = src[(size_t)(r0 + ty + i) * C + c0 + tx];
    __syncthreads();
#pragma unroll
    for (int i = 0; i < 32; i += 8)
        dst[(size_t)(c0 + ty + i) * R + r0 + tx] = (bf16)tile[tx][ty + i];
}

// ---------------- Xproj: XH[i][n] = bf16( X[i]@Wx[:,n] + bias[n] ) ----------------
__global__ __launch_bounds__(256) void k_xproj(
    const bf16* __restrict__ X, const bf16* __restrict__ Wxt,
    const float* __restrict__ bias, bf16* __restrict__ XH)
{
    __shared__ __align__(16) bf16 As[64 * LDSS];
    __shared__ __align__(16) bf16 Bs[64 * LDSS];
    const int tid  = threadIdx.x;
    const int lane = tid & 63;
    const int w    = tid >> 6;
    const int wm   = (w >> 1) * 32;
    const int wn   = (w & 1) * 32;
    const int quad = lane >> 4;
    const int l15  = lane & 15;
    const int m0 = blockIdx.x * 64;
    const int n0 = blockIdx.y * 64;

    const bf16* Ag = X + (size_t)m0 * V_SZ;
    const bf16* Bg = Wxt + (size_t)n0 * V_SZ;

    f32x4 z = {0.f, 0.f, 0.f, 0.f};
    f32x4 acc00 = z, acc01 = z, acc10 = z, acc11 = z;

    for (int k0 = 0; k0 < V_SZ; k0 += 64) {
        {
            int c = tid, row = c >> 3, col = (c & 7) * 8;
            *(bf16x8*)&As[row * LDSS + col] = *(const bf16x8*)&Ag[(size_t)row * V_SZ + k0 + col];
            *(bf16x8*)&Bs[row * LDSS + col] = *(const bf16x8*)&Bg[(size_t)row * V_SZ + k0 + col];
            c = tid + 256; row = c >> 3; col = (c & 7) * 8;
            *(bf16x8*)&As[row * LDSS + col] = *(const bf16x8*)&Ag[(size_t)row * V_SZ + k0 + col];
            *(bf16x8*)&Bs[row * LDSS + col] = *(const bf16x8*)&Bg[(size_t)row * V_SZ + k0 + col];
        }
        __syncthreads();
#pragma unroll
        for (int kc = 0; kc < 64; kc += 32) {
            bf16x8 a0 = *(const bf16x8*)&As[(wm + l15) * LDSS + kc + quad * 8];
            bf16x8 a1 = *(const bf16x8*)&As[(wm + 16 + l15) * LDSS + kc + quad * 8];
            bf16x8 b0 = *(const bf16x8*)&Bs[(wn + l15) * LDSS + kc + quad * 8];
            bf16x8 b1 = *(const bf16x8*)&Bs[(wn + 16 + l15) * LDSS + kc + quad * 8];
            acc00 = __builtin_amdgcn_mfma_f32_16x16x32_bf16(a0, b0, acc00, 0, 0, 0);
            acc01 = __builtin_amdgcn_mfma_f32_16x16x32_bf16(a0, b1, acc01, 0, 0, 0);
            acc10 = __builtin_amdgcn_mfma_f32_16x16x32_bf16(a1, b0, acc10, 0, 0, 0);
            acc11 = __builtin_amdgcn_mfma_f32_16x16x32_bf16(a1, b1, acc11, 0, 0, 0);
        }
        __syncthreads();
    }
    bf16* Out = XH + (size_t)m0 * N_SZ + n0;
    const f32x4 accs[2][2] = {{acc00, acc01}, {acc10, acc11}};
#pragma unroll
    for (int mi = 0; mi < 2; ++mi)
#pragma unroll
        for (int r = 0; r < 4; ++r) {
            int row = wm + mi * 16 + quad * 4 + r;
#pragma unroll
            for (int ni = 0; ni < 2; ++ni) {
                int col = wn + ni * 16 + l15;
                float pre = accs[mi][ni][r] + bias[n0 + col];
                Out[(size_t)row * N_SZ + col] = (bf16)pre;
            }
        }
}

// ---------------- persistent recurrence ----------------
// Grid = 256 blocks (16 row-groups x 16 col-blocks), 512 threads (8 waves).
// Block owns output tile rows [g*16, +16), cols [c*64, +64).
// Wh^T slab for those 64 cols lives in REGISTERS (wave w covers k in [w*128,+128)).
// Per step: A = XH[t-1] rows (global), MFMA K-partials, LDS reduce, +Xproj, tanh,
// write XH[t], then release-fence + per-group arrive counter (cross-XCD safe).
__global__ __launch_bounds__(512) void k_rnn(
    const bf16* __restrict__ Wht,   // 1024 x 1024 = Wh^T
    bf16* __restrict__ XH,
    int* __restrict__ cnt)          // [NGROUP * T_STEPS], zeroed
{
    __shared__ float red[8 * MT * RSTR];   // ~34 KB

    const int tid  = threadIdx.x;
    const int lane = tid & 63;
    const int w    = tid >> 6;        // 0..7
    const int quad = lane >> 4;
    const int l15  = lane & 15;
    const int g  = blockIdx.x >> 4;   // row group
    const int cb = blockIdx.x & 15;   // col block
    const int m0 = g * MT;
    const int n0 = cb * NW;
    const int k0 = w * KW;

    // ---- load Wh^T slab into registers: breg[nt][kc] ----
    bf16x8 breg[4][4];
#pragma unroll
    for (int nt = 0; nt < 4; ++nt)
#pragma unroll
        for (int kc = 0; kc < 4; ++kc)
            breg[nt][kc] = *(const bf16x8*)&Wht[(size_t)(n0 + nt * 16 + l15) * N_SZ
                                                + k0 + kc * 32 + quad * 8];

    const int o  = tid * 2;          // 1024 outputs, 2 per thread
    const int om = o >> 6;           // row in tile 0..15
    const int on = o & 63;           // col in tile (even)

    for (int t = 0; t < T_STEPS; ++t) {
        bf16* Hrow = XH + ((size_t)t * B_SZ + m0) * N_SZ;

        if (t == 0) {
            // H0 = tanh(Xproj[0])
            float x0 = (float)Hrow[(size_t)om * N_SZ + n0 + on];
            float x1 = (float)Hrow[(size_t)om * N_SZ + n0 + on + 1];
            Hrow[(size_t)om * N_SZ + n0 + on]     = (bf16)fast_tanh(x0);
            Hrow[(size_t)om * N_SZ + n0 + on + 1] = (bf16)fast_tanh(x1);
        } else {
            // ---- wait for all 16 blocks of this group to publish step t-1 ----
            if (tid == 0) {
                while (__hip_atomic_load(&cnt[g * T_STEPS + t - 1],
                                         __ATOMIC_ACQUIRE, __HIP_MEMORY_SCOPE_AGENT) < NB) {
                    __builtin_amdgcn_s_sleep(1);
                }
            }
            __syncthreads();
            __threadfence();   // acquire: invalidate stale cache for all threads

            // ---- A fragments from global: rows of H_{t-1} ----
            const bf16* Ap = XH + ((size_t)(t - 1) * B_SZ + m0 + l15) * N_SZ
                             + k0 + quad * 8;
            bf16x8 areg[4];
#pragma unroll
            for (int kc = 0; kc < 4; ++kc)
                areg[kc] = *(const bf16x8*)&Ap[kc * 32];

            f32x4 z = {0.f, 0.f, 0.f, 0.f};
            f32x4 acc[4] = {z, z, z, z};
#pragma unroll
            for (int kc = 0; kc < 4; ++kc)
#pragma unroll
                for (int nt = 0; nt < 4; ++nt)
                    acc[nt] = __builtin_amdgcn_mfma_f32_16x16x32_bf16(
                        areg[kc], breg[nt][kc], acc[nt], 0, 0, 0);

            // ---- K-reduction across 8 waves via LDS ----
#pragma unroll
            for (int nt = 0; nt < 4; ++nt)
#pragma unroll
                for (int r = 0; r < 4; ++r)
                    red[(w * MT + quad * 4 + r) * RSTR + nt * 16 + l15] = acc[nt][r];
            __syncthreads();

            float s0 = 0.f, s1 = 0.f;
#pragma unroll
            for (int w2 = 0; w2 < 8; ++w2) {
                float2 v = *(const float2*)&red[(w2 * MT + om) * RSTR + on];
                s0 += v.x; s1 += v.y;
            }
            float x0 = (float)Hrow[(size_t)om * N_SZ + n0 + on];
            float x1 = (float)Hrow[(size_t)om * N_SZ + n0 + on + 1];
            Hrow[(size_t)om * N_SZ + n0 + on]     = (bf16)fast_tanh(s0 + x0);
            Hrow[(size_t)om * N_SZ + n0 + on + 1] = (bf16)fast_tanh(s1 + x1);
            __syncthreads();   // protect red[] before next iteration's writes
        }

        // ---- publish step t ----
        __threadfence();       // release own stores to agent scope
        __syncthreads();
        if (tid == 0)
            __hip_atomic_fetch_add(&cnt[g * T_STEPS + t], 1,
                                   __ATOMIC_RELEASE, __HIP_MEMORY_SCOPE_AGENT);
    }
}

// ---------------- fused logits + log-softmax + loss ----------------
__global__ __launch_bounds__(256) void k_loss(
    const bf16* __restrict__ XH,
    const bf16* __restrict__ Wot,    // 256 x 1024 = Wout^T
    const float* __restrict__ ob,
    const float* __restrict__ labels,
    float* __restrict__ out)
{
    __shared__ __align__(16) bf16 As[64 * LDSS];
    __shared__ __align__(16) bf16 Bs[256 * LDSS];
    const int tid  = threadIdx.x;
    const int lane = tid & 63;
    const int w    = tid >> 6;
    const int quad = lane >> 4;
    const int l15  = lane & 15;
    const int m0 = blockIdx.x * 64;

    f32x4 z = {0.f, 0.f, 0.f, 0.f};
    f32x4 acc[16];
#pragma unroll
    for (int i = 0; i < 16; ++i) acc[i] = z;

    const bf16* Ag = XH + (size_t)m0 * N_SZ;
    for (int k0 = 0; k0 < N_SZ; k0 += 64) {
        {
            int c = tid, row = c >> 3, col = (c & 7) * 8;
            *(bf16x8*)&As[row * LDSS + col] = *(const bf16x8*)&Ag[(size_t)row * N_SZ + k0 + col];
            c = tid + 256; row = c >> 3; col = (c & 7) * 8;
            *(bf16x8*)&As[row * LDSS + col] = *(const bf16x8*)&Ag[(size_t)row * N_SZ + k0 + col];
        }
#pragma unroll
        for (int c = tid; c < 2048; c += 256) {
            int row = c >> 3, col = (c & 7) * 8;
            *(bf16x8*)&Bs[row * LDSS + col] = *(const bf16x8*)&Wot[(size_t)row * N_SZ + k0 + col];
        }
        __syncthreads();
#pragma unroll
        for (int kc = 0; kc < 64; kc += 32) {
            bf16x8 a = *(const bf16x8*)&As[(w * 16 + l15) * LDSS + kc + quad * 8];
#pragma unroll
            for (int nt = 0; nt < 16; ++nt) {
                bf16x8 b = *(const bf16x8*)&Bs[(nt * 16 + l15) * LDSS + kc + quad * 8];
                acc[nt] = __builtin_amdgcn_mfma_f32_16x16x32_bf16(a, b, acc[nt], 0, 0, 0);
            }
        }
        __syncthreads();
    }

    float obv[16];
#pragma unroll
    for (int nt = 0; nt < 16; ++nt) obv[nt] = ob[nt * 16 + l15];

    float total = 0.f;
#pragma unroll
    for (int r = 0; r < 4; ++r) {
        int row = m0 + w * 16 + quad * 4 + r;
        float vals[16];
        float lmax = -3.0e38f;
#pragma unroll
        for (int nt = 0; nt < 16; ++nt) {
            vals[nt] = acc[nt][r] + obv[nt];
            lmax = fmaxf(lmax, vals[nt]);
        }
#pragma unroll
        for (int s = 1; s < 16; s <<= 1)
            lmax = fmaxf(lmax, __shfl_xor(lmax, s, 64));
        float sume = 0.f, labv = 0.f, labs = 0.f;
        const float* lrow = labels + (size_t)row * V_SZ;
#pragma unroll
        for (int nt = 0; nt < 16; ++nt) {
            sume += __expf(vals[nt] - lmax);
            float lb = lrow[nt * 16 + l15];
            labv += lb * vals[nt];
            labs += lb;
        }
#pragma unroll
        for (int s = 1; s < 16; s <<= 1) {
            sume += __shfl_xor(sume, s, 64);
            labv += __shfl_xor(labv, s, 64);
            labs += __shfl_xor(labs, s, 64);
        }
        float lse = lmax + __logf(sume);
        total += labs * lse - labv;
    }
    if (l15 == 0)
        atomicAdd(out, total * (1.0f / (float)NROWS));
}

extern "C" void kernel_launch(void* const* d_in, const int* in_sizes, int n_in,
                              void* d_out, int out_size, void* d_ws, size_t ws_size,
                              hipStream_t stream)
{
    const float* inputs  = (const float*)d_in[0];
    const float* labels  = (const float*)d_in[1];
    const float* weights = (const float*)d_in[2];
    const float* bias    = (const float*)d_in[3];
    const float* out_w   = (const float*)d_in[4];
    const float* out_b   = (const float*)d_in[5];
    float* out = (float*)d_out;

    char* ws = (char*)d_ws;
    bf16* XH  = (bf16*)ws;  ws += (size_t)NROWS * N_SZ * 2;   // 64 MB, Xproj then H in place
    bf16* Xb  = (bf16*)ws;  ws += (size_t)NROWS * V_SZ * 2;   // 16 MB
    bf16* Wxt = (bf16*)ws;  ws += (size_t)N_SZ * V_SZ * 2;    // 0.5 MB (Wx^T: 1024x256)
    bf16* Wht = (bf16*)ws;  ws += (size_t)N_SZ * N_SZ * 2;    // 2 MB   (Wh^T: 1024x1024)
    bf16* Wot = (bf16*)ws;  ws += (size_t)V_SZ * N_SZ * 2;    // 0.5 MB (Wo^T: 256x1024)
    int*  cnt = (int*)ws;   ws += (size_t)NGROUP * T_STEPS * 4; // 8 KB sync counters

    hipMemsetAsync(out, 0, sizeof(float), stream);
    hipMemsetAsync(cnt, 0, (size_t)NGROUP * T_STEPS * 4, stream);

    k_convert<<<dim3(NROWS * V_SZ / 1024), 256, 0, stream>>>(inputs, Xb, NROWS * V_SZ);
    k_transpose_cvt<<<dim3(N_SZ / 32, V_SZ / 32), 256, 0, stream>>>(weights, Wxt, V_SZ, N_SZ);
    k_transpose_cvt<<<dim3(N_SZ / 32, N_SZ / 32), 256, 0, stream>>>(
        weights + (size_t)V_SZ * N_SZ, Wht, N_SZ, N_SZ);
    k_transpose_cvt<<<dim3(V_SZ / 32, N_SZ / 32), 256, 0, stream>>>(out_w, Wot, N_SZ, V_SZ);

    k_xproj<<<dim3(NROWS / 64, N_SZ / 64), 256, 0, stream>>>(Xb, Wxt, bias, XH);

    k_rnn<<<dim3(NGROUP * NB), 512, 0, stream>>>(Wht, XH, cnt);

    k_loss<<<dim3(NROWS / 64), 256, 0, stream>>>(XH, Wot, out_b, labels, out);
}

// Round 3
// 1050.071 us; speedup vs baseline: 8.8244x; 8.8244x over previous
//
#include <hip/hip_runtime.h>
#include <math.h>

typedef __bf16 bf16;
typedef __attribute__((ext_vector_type(4))) __bf16 bf16x4;
typedef __attribute__((ext_vector_type(8))) __bf16 bf16x8;
typedef __attribute__((ext_vector_type(4))) float f32x4;

#define T_STEPS 128
#define B_SZ    256
#define V_SZ    256
#define N_SZ    1024
#define NROWS   (T_STEPS * B_SZ)   // 32768
#define LDSS    72                 // padded LDS stride in elements (64 + 8)
#define RSTR    68                 // padded fp32 reduction stride

__device__ __forceinline__ float fast_tanh(float x) {
    float e = __expf(2.0f * x);
    return 1.0f - 2.0f / (e + 1.0f);   // exact at +-inf, no NaN
}

// ---------------- fp32 -> bf16 contiguous convert ----------------
__global__ void k_convert(const float* __restrict__ src, bf16* __restrict__ dst, int n) {
    int i = (blockIdx.x * blockDim.x + threadIdx.x) * 4;
    if (i < n) {
        float4 v = *(const float4*)(src + i);
        bf16x4 o;
        o.x = (bf16)v.x; o.y = (bf16)v.y; o.z = (bf16)v.z; o.w = (bf16)v.w;
        *(bf16x4*)(dst + i) = o;
    }
}

// ---------------- fp32 (R x C) -> bf16 transpose (C x R) ----------------
__global__ void k_transpose_cvt(const float* __restrict__ src, bf16* __restrict__ dst,
                                int R, int C) {
    __shared__ float tile[32][33];
    int c0 = blockIdx.x * 32;
    int r0 = blockIdx.y * 32;
    int tx = threadIdx.x & 31;
    int ty = threadIdx.x >> 5;   // 0..7
#pragma unroll
    for (int i = 0; i < 32; i += 8)
        tile[ty + i][tx] = src[(size_t)(r0 + ty + i) * C + c0 + tx];
    __syncthreads();
#pragma unroll
    for (int i = 0; i < 32; i += 8)
        dst[(size_t)(c0 + ty + i) * R + r0 + tx] = (bf16)tile[tx][ty + i];
}

// ---------------- Xproj: XH[i][n] = bf16( X[i]@Wx[:,n] + bias[n] ) ----------------
// Rows with i < B_SZ are t=0: fold in h0 = tanh(Xproj0) since h_init = 0.
__global__ __launch_bounds__(256) void k_xproj(
    const bf16* __restrict__ X, const bf16* __restrict__ Wxt,
    const float* __restrict__ bias, bf16* __restrict__ XH)
{
    __shared__ __align__(16) bf16 As[64 * LDSS];
    __shared__ __align__(16) bf16 Bs[64 * LDSS];
    const int tid  = threadIdx.x;
    const int lane = tid & 63;
    const int w    = tid >> 6;
    const int wm   = (w >> 1) * 32;
    const int wn   = (w & 1) * 32;
    const int quad = lane >> 4;
    const int l15  = lane & 15;
    const int m0 = blockIdx.x * 64;
    const int n0 = blockIdx.y * 64;

    const bf16* Ag = X + (size_t)m0 * V_SZ;
    const bf16* Bg = Wxt + (size_t)n0 * V_SZ;

    f32x4 z = {0.f, 0.f, 0.f, 0.f};
    f32x4 acc00 = z, acc01 = z, acc10 = z, acc11 = z;

    for (int k0 = 0; k0 < V_SZ; k0 += 64) {
        {
            int c = tid, row = c >> 3, col = (c & 7) * 8;
            *(bf16x8*)&As[row * LDSS + col] = *(const bf16x8*)&Ag[(size_t)row * V_SZ + k0 + col];
            *(bf16x8*)&Bs[row * LDSS + col] = *(const bf16x8*)&Bg[(size_t)row * V_SZ + k0 + col];
            c = tid + 256; row = c >> 3; col = (c & 7) * 8;
            *(bf16x8*)&As[row * LDSS + col] = *(const bf16x8*)&Ag[(size_t)row * V_SZ + k0 + col];
            *(bf16x8*)&Bs[row * LDSS + col] = *(const bf16x8*)&Bg[(size_t)row * V_SZ + k0 + col];
        }
        __syncthreads();
#pragma unroll
        for (int kc = 0; kc < 64; kc += 32) {
            bf16x8 a0 = *(const bf16x8*)&As[(wm + l15) * LDSS + kc + quad * 8];
            bf16x8 a1 = *(const bf16x8*)&As[(wm + 16 + l15) * LDSS + kc + quad * 8];
            bf16x8 b0 = *(const bf16x8*)&Bs[(wn + l15) * LDSS + kc + quad * 8];
            bf16x8 b1 = *(const bf16x8*)&Bs[(wn + 16 + l15) * LDSS + kc + quad * 8];
            acc00 = __builtin_amdgcn_mfma_f32_16x16x32_bf16(a0, b0, acc00, 0, 0, 0);
            acc01 = __builtin_amdgcn_mfma_f32_16x16x32_bf16(a0, b1, acc01, 0, 0, 0);
            acc10 = __builtin_amdgcn_mfma_f32_16x16x32_bf16(a1, b0, acc10, 0, 0, 0);
            acc11 = __builtin_amdgcn_mfma_f32_16x16x32_bf16(a1, b1, acc11, 0, 0, 0);
        }
        __syncthreads();
    }
    bf16* Out = XH + (size_t)m0 * N_SZ + n0;
    const f32x4 accs[2][2] = {{acc00, acc01}, {acc10, acc11}};
#pragma unroll
    for (int mi = 0; mi < 2; ++mi)
#pragma unroll
        for (int r = 0; r < 4; ++r) {
            int row = wm + mi * 16 + quad * 4 + r;
            bool is_t0 = (m0 + row) < B_SZ;   // t=0 rows: apply tanh (h_prev = 0)
#pragma unroll
            for (int ni = 0; ni < 2; ++ni) {
                int col = wn + ni * 16 + l15;
                float pre = accs[mi][ni][r] + bias[n0 + col];
                if (is_t0) pre = fast_tanh(pre);
                Out[(size_t)row * N_SZ + col] = (bf16)pre;
            }
        }
}

// ---------------- recurrent step: XH[t] = tanh(XH[t] + XH[t-1] @ Wh), t >= 1 --------
// Grid (16,16) = 256 blocks (one per CU), 512 threads = 8 waves, K-split 128/wave.
// B (Wh^T slab) and A (H_{t-1} rows) read straight from L2 into registers;
// LDS only for the 8-wave K-reduction. One barrier per step.
__global__ __launch_bounds__(512) void k_step(
    const bf16* __restrict__ Wht,   // 1024 x 1024 = Wh^T
    bf16* __restrict__ XH, int t)
{
    __shared__ float red[8 * 16 * RSTR];   // 34.8 KB
    const int tid  = threadIdx.x;
    const int lane = tid & 63;
    const int w    = tid >> 6;        // 0..7
    const int quad = lane >> 4;
    const int l15  = lane & 15;
    const int m0 = blockIdx.x * 16;
    const int n0 = blockIdx.y * 64;
    const int k0 = w * 128;

    // A fragments: rows m0+l15 of H_{t-1}, k in [k0, k0+128)
    const bf16* Ap = XH + ((size_t)(t - 1) * B_SZ + m0 + l15) * N_SZ + k0 + quad * 8;
    bf16x8 areg[4];
#pragma unroll
    for (int kc = 0; kc < 4; ++kc)
        areg[kc] = *(const bf16x8*)&Ap[kc * 32];

    f32x4 z = {0.f, 0.f, 0.f, 0.f};
    f32x4 acc[4] = {z, z, z, z};
    const bf16* Bp = Wht + (size_t)(n0 + l15) * N_SZ + k0 + quad * 8;
#pragma unroll
    for (int nt = 0; nt < 4; ++nt)
#pragma unroll
        for (int kc = 0; kc < 4; ++kc) {
            bf16x8 b = *(const bf16x8*)&Bp[(size_t)(nt * 16) * N_SZ + kc * 32];
            acc[nt] = __builtin_amdgcn_mfma_f32_16x16x32_bf16(areg[kc], b, acc[nt], 0, 0, 0);
        }

    // K-reduction across 8 waves via LDS
#pragma unroll
    for (int nt = 0; nt < 4; ++nt)
#pragma unroll
        for (int r = 0; r < 4; ++r)
            red[(w * 16 + quad * 4 + r) * RSTR + nt * 16 + l15] = acc[nt][r];
    __syncthreads();

    const int o  = tid * 2;          // 1024 outputs, 2 per thread
    const int om = o >> 6;
    const int on = o & 63;
    float s0 = 0.f, s1 = 0.f;
#pragma unroll
    for (int w2 = 0; w2 < 8; ++w2) {
        float2 v = *(const float2*)&red[(w2 * 16 + om) * RSTR + on];
        s0 += v.x; s1 += v.y;
    }
    bf16* Hp = XH + ((size_t)t * B_SZ + m0 + om) * N_SZ + n0 + on;
    s0 += (float)Hp[0];
    s1 += (float)Hp[1];
    Hp[0] = (bf16)fast_tanh(s0);
    Hp[1] = (bf16)fast_tanh(s1);
}

// ---------------- fused logits + log-softmax + loss ----------------
__global__ __launch_bounds__(256) void k_loss(
    const bf16* __restrict__ XH,
    const bf16* __restrict__ Wot,    // 256 x 1024 = Wout^T
    const float* __restrict__ ob,
    const float* __restrict__ labels,
    float* __restrict__ out)
{
    __shared__ __align__(16) bf16 As[64 * LDSS];
    __shared__ __align__(16) bf16 Bs[256 * LDSS];
    const int tid  = threadIdx.x;
    const int lane = tid & 63;
    const int w    = tid >> 6;
    const int quad = lane >> 4;
    const int l15  = lane & 15;
    const int m0 = blockIdx.x * 64;

    f32x4 z = {0.f, 0.f, 0.f, 0.f};
    f32x4 acc[16];
#pragma unroll
    for (int i = 0; i < 16; ++i) acc[i] = z;

    const bf16* Ag = XH + (size_t)m0 * N_SZ;
    for (int k0 = 0; k0 < N_SZ; k0 += 64) {
        {
            int c = tid, row = c >> 3, col = (c & 7) * 8;
            *(bf16x8*)&As[row * LDSS + col] = *(const bf16x8*)&Ag[(size_t)row * N_SZ + k0 + col];
            c = tid + 256; row = c >> 3; col = (c & 7) * 8;
            *(bf16x8*)&As[row * LDSS + col] = *(const bf16x8*)&Ag[(size_t)row * N_SZ + k0 + col];
        }
#pragma unroll
        for (int c = tid; c < 2048; c += 256) {
            int row = c >> 3, col = (c & 7) * 8;
            *(bf16x8*)&Bs[row * LDSS + col] = *(const bf16x8*)&Wot[(size_t)row * N_SZ + k0 + col];
        }
        __syncthreads();
#pragma unroll
        for (int kc = 0; kc < 64; kc += 32) {
            bf16x8 a = *(const bf16x8*)&As[(w * 16 + l15) * LDSS + kc + quad * 8];
#pragma unroll
            for (int nt = 0; nt < 16; ++nt) {
                bf16x8 b = *(const bf16x8*)&Bs[(nt * 16 + l15) * LDSS + kc + quad * 8];
                acc[nt] = __builtin_amdgcn_mfma_f32_16x16x32_bf16(a, b, acc[nt], 0, 0, 0);
            }
        }
        __syncthreads();
    }

    float obv[16];
#pragma unroll
    for (int nt = 0; nt < 16; ++nt) obv[nt] = ob[nt * 16 + l15];

    float total = 0.f;
#pragma unroll
    for (int r = 0; r < 4; ++r) {
        int row = m0 + w * 16 + quad * 4 + r;
        float vals[16];
        float lmax = -3.0e38f;
#pragma unroll
        for (int nt = 0; nt < 16; ++nt) {
            vals[nt] = acc[nt][r] + obv[nt];
            lmax = fmaxf(lmax, vals[nt]);
        }
#pragma unroll
        for (int s = 1; s < 16; s <<= 1)
            lmax = fmaxf(lmax, __shfl_xor(lmax, s, 64));
        float sume = 0.f, labv = 0.f, labs = 0.f;
        const float* lrow = labels + (size_t)row * V_SZ;
#pragma unroll
        for (int nt = 0; nt < 16; ++nt) {
            sume += __expf(vals[nt] - lmax);
            float lb = lrow[nt * 16 + l15];
            labv += lb * vals[nt];
            labs += lb;
        }
#pragma unroll
        for (int s = 1; s < 16; s <<= 1) {
            sume += __shfl_xor(sume, s, 64);
            labv += __shfl_xor(labv, s, 64);
            labs += __shfl_xor(labs, s, 64);
        }
        float lse = lmax + __logf(sume);
        total += labs * lse - labv;
    }
    if (l15 == 0)
        atomicAdd(out, total * (1.0f / (float)NROWS));
}

extern "C" void kernel_launch(void* const* d_in, const int* in_sizes, int n_in,
                              void* d_out, int out_size, void* d_ws, size_t ws_size,
                              hipStream_t stream)
{
    const float* inputs  = (const float*)d_in[0];
    const float* labels  = (const float*)d_in[1];
    const float* weights = (const float*)d_in[2];
    const float* bias    = (const float*)d_in[3];
    const float* out_w   = (const float*)d_in[4];
    const float* out_b   = (const float*)d_in[5];
    float* out = (float*)d_out;

    char* ws = (char*)d_ws;
    bf16* XH  = (bf16*)ws;  ws += (size_t)NROWS * N_SZ * 2;   // 64 MB, Xproj then H in place
    bf16* Xb  = (bf16*)ws;  ws += (size_t)NROWS * V_SZ * 2;   // 16 MB
    bf16* Wxt = (bf16*)ws;  ws += (size_t)N_SZ * V_SZ * 2;    // 0.5 MB (Wx^T: 1024x256)
    bf16* Wht = (bf16*)ws;  ws += (size_t)N_SZ * N_SZ * 2;    // 2 MB   (Wh^T: 1024x1024)
    bf16* Wot = (bf16*)ws;  ws += (size_t)V_SZ * N_SZ * 2;    // 0.5 MB (Wo^T: 256x1024)

    hipMemsetAsync(out, 0, sizeof(float), stream);

    k_convert<<<dim3(NROWS * V_SZ / 1024), 256, 0, stream>>>(inputs, Xb, NROWS * V_SZ);
    k_transpose_cvt<<<dim3(N_SZ / 32, V_SZ / 32), 256, 0, stream>>>(weights, Wxt, V_SZ, N_SZ);
    k_transpose_cvt<<<dim3(N_SZ / 32, N_SZ / 32), 256, 0, stream>>>(
        weights + (size_t)V_SZ * N_SZ, Wht, N_SZ, N_SZ);
    k_transpose_cvt<<<dim3(V_SZ / 32, N_SZ / 32), 256, 0, stream>>>(out_w, Wot, N_SZ, V_SZ);

    k_xproj<<<dim3(NROWS / 64, N_SZ / 64), 256, 0, stream>>>(Xb, Wxt, bias, XH);

    for (int t = 1; t < T_STEPS; ++t)
        k_step<<<dim3(B_SZ / 16, N_SZ / 64), 512, 0, stream>>>(Wht, XH, t);

    k_loss<<<dim3(NROWS / 64), 256, 0, stream>>>(XH, Wot, out_b, labels, out);
}